// Round 1
// baseline (152.646 us; speedup 1.0000x reference)
//
#include <hip/hip_runtime.h>
#include <math.h>

constexpr int HS = 360, WS = 640, NPIX = HS * WS;
constexpr int NSQ = 8, NSAMP = 10, NPT = NSAMP + 2;
constexpr float FARV = 1.5f, TAUV = 100.0f, SHARPV = 1000.0f, EPSV = 1e-6f;

struct SQ {
  float R[9];      // R[k*3+j] = sq_poses[n, k, j]
  float tc[3];     // R^T (rays_o - p) / sizes
  float inv_s[3];
  float s0, s1, s2;
  float c2, c21, c1, e1;   // 2/e2, e2/e1, 2/e1, e1
};

__device__ __forceinline__ float sq_F(float X0, float X1, float X2, const SQ& q) {
  float A = powf(X0, q.c2);
  float B = powf(X1, q.c2);
  float C = powf(X2, q.c1);
  float f = powf(A + B, q.c21) + C;
  return powf(f, q.e1);
}

__global__ __launch_bounds__(256) void depth_kernel(
    const float* __restrict__ poses, const float* __restrict__ params,
    const float* __restrict__ rays_d, const float* __restrict__ rays_o,
    const float* __restrict__ tt, float* __restrict__ out)
{
  __shared__ SQ sq[NSQ];
  __shared__ float t_sh[NSAMP];
  const int tid = threadIdx.x;

  if (tid < NSQ) {
    const int n = tid;
    const float* P = poses + n * 16;
    const float* par = params + n * 5;
    SQ q;
#pragma unroll
    for (int i = 0; i < 3; i++)
#pragma unroll
      for (int j = 0; j < 3; j++)
        q.R[i * 3 + j] = P[i * 4 + j];
    const float p0 = P[3], p1 = P[7], p2 = P[11];
    const float s0 = par[0], s1 = par[1], s2 = par[2];
    const float e1 = par[3], e2 = par[4];
    q.s0 = s0; q.s1 = s1; q.s2 = s2;
    q.inv_s[0] = 1.0f / s0; q.inv_s[1] = 1.0f / s1; q.inv_s[2] = 1.0f / s2;
    const float ro0 = rays_o[0], ro1 = rays_o[1], ro2 = rays_o[2];
    const float d0 = ro0 - p0, d1 = ro1 - p1, d2 = ro2 - p2;
    q.tc[0] = (q.R[0] * d0 + q.R[3] * d1 + q.R[6] * d2) * q.inv_s[0];
    q.tc[1] = (q.R[1] * d0 + q.R[4] * d1 + q.R[7] * d2) * q.inv_s[1];
    q.tc[2] = (q.R[2] * d0 + q.R[5] * d1 + q.R[8] * d2) * q.inv_s[2];
    q.c2 = 2.0f / e2; q.c21 = e2 / e1; q.c1 = 2.0f / e1; q.e1 = e1;
    sq[n] = q;
  }
  if (tid >= 64 && tid < 64 + NSAMP) t_sh[tid - 64] = tt[tid - 64];
  __syncthreads();

  const int pix = blockIdx.x * blockDim.x + tid;
  if (pix >= NPIX) return;

  const float rd0 = rays_d[pix * 3 + 0];
  const float rd1 = rays_d[pix * 3 + 1];
  const float rd2 = rays_d[pix * 3 + 2];

  float m = FARV;

  for (int n = 0; n < NSQ; n++) {
    const SQ& q = sq[n];
    // u = R^T d, then scale by 1/sizes
    const float u0 = q.R[0] * rd0 + q.R[3] * rd1 + q.R[6] * rd2;
    const float u1 = q.R[1] * rd0 + q.R[4] * rd1 + q.R[7] * rd2;
    const float u2 = q.R[2] * rd0 + q.R[5] * rd1 + q.R[8] * rd2;
    const float w0 = u0 * q.inv_s[0], w1 = u1 * q.inv_s[1], w2 = u2 * q.inv_s[2];
    const float lam2 = w0 * w0 + w1 * w1 + w2 * w2;
    const float lam = sqrtf(lam2);
    const float invl = 1.0f / lam;
    const float td0 = w0 * invl, td1 = w1 * invl, td2 = w2 * invl;
    const float tc0 = q.tc[0], tc1 = q.tc[1], tc2 = q.tc[2];

    const float dd = tc0 * td0 + tc1 * td1 + tc2 * td2;
    const float proj = fabsf(dd);
    const float ce0 = tc0 + proj * td0;
    const float ce1 = tc1 + proj * td1;
    const float ce2 = tc2 + proj * td2;
    const float dist2 = ce0 * ce0 + ce1 * ce1 + ce2 * ce2;
    if (!(dist2 < 3.0f)) continue;   // mask: dist < sqrt(3)

    const float hcl = sqrtf(fmaxf(3.0f - dist2, 1e-12f));
    const float gs0 = td0 * q.s0, gs1 = td1 * q.s1, gs2 = td2 * q.s2;
    const float g = sqrtf(gs0 * gs0 + gs1 * gs1 + gs2 * gs2);

    float alpha[NPT];
    alpha[0] = 0.0f;
#pragma unroll
    for (int s = 0; s < NSAMP; s++) alpha[s + 1] = proj + hcl * t_sh[s];
    alpha[NPT - 1] = FARV * lam;

    float csum = 0.0f, vp = 0.0f, depth = 0.0f;
#pragma unroll
    for (int k = 0; k < NPT; k++) {
      const float a = alpha[k];
      const float X0 = fabsf(tc0 + a * td0) + EPSV;
      const float X1 = fabsf(tc1 + a * td1) + EPSV;
      const float X2 = fabsf(tc2 + a * td2) + EPSV;
      const float F = sq_F(X0, X1, X2, q);
      // occ = sigmoid(SHARP*(1-F)) = 1/(1+exp(SHARP*(F-1)))
      const float occ = 1.0f / (1.0f + expf(SHARPV * (F - 1.0f)));
      csum += occ;
      const float vis = expf(-TAUV * csum);
      if (k) depth += 0.5f * (vp + vis) * fabsf(a - alpha[k - 1]) * g;
      vp = vis;
    }
    m = fminf(m, depth);
  }

  out[pix] = m;
}

extern "C" void kernel_launch(void* const* d_in, const int* in_sizes, int n_in,
                              void* d_out, int out_size, void* d_ws, size_t ws_size,
                              hipStream_t stream) {
  const float* poses  = (const float*)d_in[0];
  const float* params = (const float*)d_in[1];
  const float* rays_d = (const float*)d_in[2];
  const float* rays_o = (const float*)d_in[3];
  const float* t      = (const float*)d_in[4];
  float* out = (float*)d_out;

  const int block = 256;
  const int grid = (NPIX + block - 1) / block;
  depth_kernel<<<grid, block, 0, stream>>>(poses, params, rays_d, rays_o, t, out);
}

// Round 2
// 27.589 us; speedup vs baseline: 5.5328x; 5.5328x over previous
//
#include <hip/hip_runtime.h>
#include <math.h>

constexpr int HS = 360, WS = 640, NPIX = HS * WS;
constexpr int NSQ = 8, NSAMP = 10, NPT = NSAMP + 2;
constexpr float FARV = 1.5f, TAUV = 100.0f, SHARPV = 1000.0f, EPSV = 1e-6f;

struct SQ {
  float R[9];      // R[k*3+j] = sq_poses[n, k, j]
  float tc[3];     // R^T (rays_o - p) / sizes
  float inv_s[3];
  float s0, s1, s2;
  float c2, c21, c1, e1;   // 2/e2, e2/e1, 2/e1, e1
};

// fast pow via HW v_log_f32 / v_exp_f32 (x > 0 guaranteed: x >= EPS)
__device__ __forceinline__ float fpow(float x, float c) {
  return __expf(c * __logf(x));
}

__global__ __launch_bounds__(256) void depth_kernel(
    const float* __restrict__ poses, const float* __restrict__ params,
    const float* __restrict__ rays_d, const float* __restrict__ rays_o,
    const float* __restrict__ tt, float* __restrict__ out)
{
  __shared__ SQ sq[NSQ];
  __shared__ float t_sh[NSAMP];
  const int tid = threadIdx.x;

  if (tid < NSQ) {
    const int n = tid;
    const float* P = poses + n * 16;
    const float* par = params + n * 5;
    SQ q;
#pragma unroll
    for (int i = 0; i < 3; i++)
#pragma unroll
      for (int j = 0; j < 3; j++)
        q.R[i * 3 + j] = P[i * 4 + j];
    const float p0 = P[3], p1 = P[7], p2 = P[11];
    const float s0 = par[0], s1 = par[1], s2 = par[2];
    const float e1 = par[3], e2 = par[4];
    q.s0 = s0; q.s1 = s1; q.s2 = s2;
    q.inv_s[0] = 1.0f / s0; q.inv_s[1] = 1.0f / s1; q.inv_s[2] = 1.0f / s2;
    const float ro0 = rays_o[0], ro1 = rays_o[1], ro2 = rays_o[2];
    const float d0 = ro0 - p0, d1 = ro1 - p1, d2 = ro2 - p2;
    q.tc[0] = (q.R[0] * d0 + q.R[3] * d1 + q.R[6] * d2) * q.inv_s[0];
    q.tc[1] = (q.R[1] * d0 + q.R[4] * d1 + q.R[7] * d2) * q.inv_s[1];
    q.tc[2] = (q.R[2] * d0 + q.R[5] * d1 + q.R[8] * d2) * q.inv_s[2];
    q.c2 = 2.0f / e2; q.c21 = e2 / e1; q.c1 = 2.0f / e1; q.e1 = e1;
    sq[n] = q;
  }
  if (tid >= 64 && tid < 64 + NSAMP) t_sh[tid - 64] = tt[tid - 64];
  __syncthreads();

  const int pix = blockIdx.x * blockDim.x + tid;
  if (pix >= NPIX) return;

  const float rd0 = rays_d[pix * 3 + 0];
  const float rd1 = rays_d[pix * 3 + 1];
  const float rd2 = rays_d[pix * 3 + 2];

  float m = FARV;

  for (int n = 0; n < NSQ; n++) {
    const SQ& q = sq[n];
    // u = R^T d, then scale by 1/sizes
    const float u0 = q.R[0] * rd0 + q.R[3] * rd1 + q.R[6] * rd2;
    const float u1 = q.R[1] * rd0 + q.R[4] * rd1 + q.R[7] * rd2;
    const float u2 = q.R[2] * rd0 + q.R[5] * rd1 + q.R[8] * rd2;
    const float w0 = u0 * q.inv_s[0], w1 = u1 * q.inv_s[1], w2 = u2 * q.inv_s[2];
    const float lam2 = w0 * w0 + w1 * w1 + w2 * w2;
    const float lam = sqrtf(lam2);
    const float invl = 1.0f / lam;
    const float td0 = w0 * invl, td1 = w1 * invl, td2 = w2 * invl;
    const float tc0 = q.tc[0], tc1 = q.tc[1], tc2 = q.tc[2];

    const float dd = tc0 * td0 + tc1 * td1 + tc2 * td2;
    const float proj = fabsf(dd);
    const float ce0 = tc0 + proj * td0;
    const float ce1 = tc1 + proj * td1;
    const float ce2 = tc2 + proj * td2;
    const float dist2 = ce0 * ce0 + ce1 * ce1 + ce2 * ce2;
    if (!(dist2 < 3.0f)) continue;   // mask: dist < sqrt(3)

    const float hcl = sqrtf(fmaxf(3.0f - dist2, 1e-12f));
    const float gs0 = td0 * q.s0, gs1 = td1 * q.s1, gs2 = td2 * q.s2;
    const float g = sqrtf(gs0 * gs0 + gs1 * gs1 + gs2 * gs2);

    float alpha[NPT];
    alpha[0] = 0.0f;
#pragma unroll
    for (int s = 0; s < NSAMP; s++) alpha[s + 1] = proj + hcl * t_sh[s];
    alpha[NPT - 1] = FARV * lam;

    // precompute all occ values (independent -> ILP across the 12 points)
    float occ[NPT];
#pragma unroll
    for (int k = 0; k < NPT; k++) {
      const float a = alpha[k];
      const float X0 = fabsf(tc0 + a * td0) + EPSV;
      const float X1 = fabsf(tc1 + a * td1) + EPSV;
      const float X2 = fabsf(tc2 + a * td2) + EPSV;
      const float A = fpow(X0, q.c2);
      const float B = fpow(X1, q.c2);
      const float C = fpow(X2, q.c1);
      const float f = fpow(A + B, q.c21) + C;
      const float F = fpow(f, q.e1);
      occ[k] = __builtin_amdgcn_rcpf(1.0f + __expf(SHARPV * (F - 1.0f)));
    }

    float csum = 0.0f, vp = 0.0f, depth = 0.0f;
#pragma unroll
    for (int k = 0; k < NPT; k++) {
      csum += occ[k];
      const float vis = __expf(-TAUV * csum);
      if (k) depth += 0.5f * (vp + vis) * fabsf(alpha[k] - alpha[k - 1]);
      vp = vis;
    }
    m = fminf(m, depth * g);
  }

  out[pix] = m;
}

extern "C" void kernel_launch(void* const* d_in, const int* in_sizes, int n_in,
                              void* d_out, int out_size, void* d_ws, size_t ws_size,
                              hipStream_t stream) {
  const float* poses  = (const float*)d_in[0];
  const float* params = (const float*)d_in[1];
  const float* rays_d = (const float*)d_in[2];
  const float* rays_o = (const float*)d_in[3];
  const float* t      = (const float*)d_in[4];
  float* out = (float*)d_out;

  const int block = 256;
  const int grid = (NPIX + block - 1) / block;
  depth_kernel<<<grid, block, 0, stream>>>(poses, params, rays_d, rays_o, t, out);
}